// Round 13
// baseline (2235.154 us; speedup 1.0000x reference)
//
#include <hip/hip_runtime.h>

// SimpleRNN: VOCAB=32000, EMBED=256, HIDDEN=512, N=256, L=512
// out = h_512 (256x512 f32), h_{t+1} = tanh(h W_hh^T + b_hh + b_xh + emb[X] W_xh^T)
//
// Round-13 = r8's structure (W-tail streamed from L2, LDS = h-dbuf only) with
// the staging slimmed to fit the empirical 128-VGPR cap:
//  - tail staged in 2-frag batches (8 regs), max 4 in flight (32 regs total,
//    was 64), issued ~3 MFMA-groups (>=250 cyc) ahead of use >= L2 latency.
//  - acc initialized from prefetched xp (kills epilogue adds).
//  Live VGPR ~95 < 128 (r8 was ~133 -> 5-reg in-loop spill, WRITE_SIZE 10MB).
//  W-head kt0..11 (192 regs) + acc stay AGPR-resident (r6-proven fit).
//  Verifier: WRITE_SIZE must be 512KB (out only). 10MB => spilled again.

typedef _Float16 f16;
typedef f16 f16x8 __attribute__((ext_vector_type(8)));
typedef float f32x4 __attribute__((ext_vector_type(4)));
typedef unsigned short u16;

union U8 { uint4 u; f16x8 h; };
union U4 { uint2 u; f16 h[4]; };

// ---------------------------------------------------------------- preconv ---
// One frag = 64 lanes x 8 f16 (1KB). lane l supplies W[col][k]:
//   col = c16*16 + (l&15), k = kt*32 + (l>>4)*8 + j.
// mode 0 (W_xh, K=256): f = c16*8 + kt                        [known-good]
// mode 1 (W_hh, K=512): kt<12 : f = kt*32 + w*4 + mt          [head, AGPR]
//                       kt>=12: f = 384 + w*16 + mt*4 + (kt-12) [tail, L2-stream]
__global__ void preconv_kernel(const float* __restrict__ W, u16* __restrict__ dst,
                               int kstride, int mode) {
  int t = blockIdx.x * blockDim.x + threadIdx.x;
  int f = t >> 6, l = t & 63;
  int kt, w, nt;
  if (mode == 0)    { kt = f & 7;  nt = (f >> 3) & 3; w = f >> 5; }
  else if (f < 384) { nt = f & 3;  w = (f >> 2) & 7;  kt = f >> 5; }
  else { int g = f - 384; kt = 12 + (g & 3); nt = (g >> 2) & 3; w = g >> 4; }
  int col = w * 64 + nt * 16 + (l & 15);
  int k   = kt * 32 + (l >> 4) * 8;
  const float* src = W + (size_t)col * kstride + k;
  float4 v0 = *(const float4*)src;
  float4 v1 = *(const float4*)(src + 4);
  U8 r;
  r.h = (f16x8){(f16)v0.x, (f16)v0.y, (f16)v0.z, (f16)v0.w,
                (f16)v1.x, (f16)v1.y, (f16)v1.z, (f16)v1.w};
  *(uint4*)(dst + (size_t)f * 512 + l * 8) = r.u;
}

// ----------------------------------------------------------------- phaseA ---
// Round-6 exact (known-good). Grid 1024 = 16 bn x 64 bl. 512 thr, 8 waves.
// Writes xpf[t][cq][n][4] f16, cq = out_col>>2 (0..127), n = batch row, biases folded.
__global__ __launch_bounds__(512, 2) void phaseA_kernel(
    const int* __restrict__ X, const float* __restrict__ emb,
    const u16* __restrict__ Wxf, const float* __restrict__ b_hh,
    const float* __restrict__ b_xh, u16* __restrict__ xpf) {
  __shared__ f16 A[128 * 256];  // 64 KB
  const int tid = threadIdx.x, w = tid >> 6, l = tid & 63;
  const int b = blockIdx.x, bn = b >> 6, bl = b & 63;
  const int lr = l & 15, lg = l >> 4;

  f16x8 wx[4][8];
#pragma unroll
  for (int mt = 0; mt < 4; ++mt)
#pragma unroll
    for (int kt = 0; kt < 8; ++kt) {
      U8 u; u.u = *(const uint4*)(Wxf + (size_t)((w * 4 + mt) * 8 + kt) * 512 + l * 8);
      wx[mt][kt] = u.h;
    }
  float bias[4][4];
#pragma unroll
  for (int mt = 0; mt < 4; ++mt)
#pragma unroll
    for (int r = 0; r < 4; ++r) {
      int c = w * 64 + mt * 16 + lg * 4 + r;
      bias[mt][r] = b_hh[c] + b_xh[c];
    }

  int xs[16];
  const int lseq = bl * 8 + w;
#pragma unroll
  for (int i = 0; i < 16; ++i) xs[i] = X[(bn * 16 + i) * 512 + lseq];
#pragma unroll
  for (int i = 0; i < 16; ++i) {
    float4 v = *(const float4*)(emb + (size_t)xs[i] * 256 + l * 4);
    U4 p; p.h[0] = (f16)v.x; p.h[1] = (f16)v.y; p.h[2] = (f16)v.z; p.h[3] = (f16)v.w;
    int row = w * 16 + i;
    *(uint2*)(&A[row * 256 + ((l * 4) ^ ((row & 7) << 3))]) = p.u;
  }
  __syncthreads();

#pragma unroll 1
  for (int nt = 0; nt < 8; ++nt) {
    f32x4 acc[4];
#pragma unroll
    for (int mt = 0; mt < 4; ++mt) acc[mt] = (f32x4){0.f, 0.f, 0.f, 0.f};
    const f16* Brow = &A[(nt * 16 + lr) * 256];
    const int sw = (lr & 7) << 3;
#pragma unroll
    for (int kt = 0; kt < 8; ++kt) {
      f16x8 bfr = *(const f16x8*)(Brow + ((kt * 32 + lg * 8) ^ sw));
#pragma unroll
      for (int mt = 0; mt < 4; ++mt)
        acc[mt] = __builtin_amdgcn_mfma_f32_16x16x32_f16(wx[mt][kt], bfr, acc[mt], 0, 0, 0);
    }
    const int t = bl * 8 + nt;
#pragma unroll
    for (int mt = 0; mt < 4; ++mt) {
      U4 p;
#pragma unroll
      for (int r = 0; r < 4; ++r) p.h[r] = (f16)(acc[mt][r] + bias[mt][r]);
      *(uint2*)(xpf + (size_t)t * 131072 + (w * 16 + mt * 4 + lg) * 1024
                    + (bn * 16 + lr) * 4) = p.u;
    }
  }
}

// ----------------------------------------------------------------- phaseB ---
// 16 blocks x 512 thr (8 waves, 2/SIMD). Block bb: batch rows [16bb,16bb+16).
// Wave w: out cols [64w,64w+64). h[16][512] f16 dbuf in static LDS (32 KB),
// storage rule: h[row][col] at u16 idx row*512 + (col ^ ((row&7)<<3)).
// W: kt0..11 AGPR-resident; kt12..15 streamed from L2 in 2-frag batches
// (s0..s3, 8 regs each, <=4 in flight), issued >=3 MFMA-groups before use.

#define HFRAG(HR, KT) (*(const f16x8*)((HR) + lr * 512 + (((KT) * 32 + lg * 8) ^ asw)))

#define MF_HEAD(HR, KT)                                                           \
  do { f16x8 hf = HFRAG(HR, KT);                                                  \
    _Pragma("unroll")                                                             \
    for (int mt = 0; mt < 4; ++mt)                                                \
      acc[mt] = __builtin_amdgcn_mfma_f32_16x16x32_f16(wa[KT][mt], hf, acc[mt], 0, 0, 0); \
  } while (0)

// load 2 tail frags (mt = M2, M2+1) of tail k-tile KT (12..15): 8 VGPRs
#define TL2(S, M2, KT)                                                            \
  do {                                                                            \
    S[0].u = *(const uint4*)(gt + (size_t)((M2) * 4 + ((KT) - 12)) * 512);        \
    S[1].u = *(const uint4*)(gt + (size_t)((M2 + 1) * 4 + ((KT) - 12)) * 512);    \
  } while (0)

#define STEP(T, HR, HW, XPc, XPn)                                                 \
  do {                                                                            \
    { /* prefetch xp for step T+1 (clamped, in-bounds) */                         \
      const int tn = ((T) + 1 < 512) ? ((T) + 1) : 511;                           \
      const u16* p = xpb + (size_t)tn * 131072;                                   \
      _Pragma("unroll")                                                           \
      for (int mt = 0; mt < 4; ++mt) XPn[mt] = *(const uint2*)(p + mt * 4096);    \
    }                                                                             \
    f32x4 acc[4];                                                                 \
    _Pragma("unroll")  /* init acc from xp prefetched LAST step (no stall) */     \
    for (int mt = 0; mt < 4; ++mt) {                                              \
      U4 px; px.u = XPc[mt];                                                      \
      acc[mt] = (f32x4){(float)px.h[0], (float)px.h[1],                           \
                        (float)px.h[2], (float)px.h[3]};                          \
    }                                                                             \
    U8 s0[2], s1[2], s2[2], s3[2];                                                \
    MF_HEAD(HR, 0); MF_HEAD(HR, 1); MF_HEAD(HR, 2); MF_HEAD(HR, 3);               \
    MF_HEAD(HR, 4); MF_HEAD(HR, 5); MF_HEAD(HR, 6); MF_HEAD(HR, 7);               \
    MF_HEAD(HR, 8);  TL2(s0, 0, 12);                                              \
    MF_HEAD(HR, 9);  TL2(s1, 2, 12);                                              \
    MF_HEAD(HR, 10); TL2(s2, 0, 13);                                              \
    MF_HEAD(HR, 11); TL2(s3, 2, 13);                                              \
    {                                                                             \
      f16x8 hf12 = HFRAG(HR, 12);                                                 \
      acc[0] = __builtin_amdgcn_mfma_f32_16x16x32_f16(s0[0].h, hf12, acc[0], 0, 0, 0); \
      acc[1] = __builtin_amdgcn_mfma_f32_16x16x32_f16(s0[1].h, hf12, acc[1], 0, 0, 0); \
      TL2(s0, 0, 14);                                                             \
      acc[2] = __builtin_amdgcn_mfma_f32_16x16x32_f16(s1[0].h, hf12, acc[2], 0, 0, 0); \
      acc[3] = __builtin_amdgcn_mfma_f32_16x16x32_f16(s1[1].h, hf12, acc[3], 0, 0, 0); \
      TL2(s1, 2, 14);                                                             \
      f16x8 hf13 = HFRAG(HR, 13);                                                 \
      acc[0] = __builtin_amdgcn_mfma_f32_16x16x32_f16(s2[0].h, hf13, acc[0], 0, 0, 0); \
      acc[1] = __builtin_amdgcn_mfma_f32_16x16x32_f16(s2[1].h, hf13, acc[1], 0, 0, 0); \
      TL2(s2, 0, 15);                                                             \
      acc[2] = __builtin_amdgcn_mfma_f32_16x16x32_f16(s3[0].h, hf13, acc[2], 0, 0, 0); \
      acc[3] = __builtin_amdgcn_mfma_f32_16x16x32_f16(s3[1].h, hf13, acc[3], 0, 0, 0); \
      TL2(s3, 2, 15);                                                             \
      f16x8 hf14 = HFRAG(HR, 14);                                                 \
      acc[0] = __builtin_amdgcn_mfma_f32_16x16x32_f16(s0[0].h, hf14, acc[0], 0, 0, 0); \
      acc[1] = __builtin_amdgcn_mfma_f32_16x16x32_f16(s0[1].h, hf14, acc[1], 0, 0, 0); \
      acc[2] = __builtin_amdgcn_mfma_f32_16x16x32_f16(s1[0].h, hf14, acc[2], 0, 0, 0); \
      acc[3] = __builtin_amdgcn_mfma_f32_16x16x32_f16(s1[1].h, hf14, acc[3], 0, 0, 0); \
      f16x8 hf15 = HFRAG(HR, 15);                                                 \
      acc[0] = __builtin_amdgcn_mfma_f32_16x16x32_f16(s2[0].h, hf15, acc[0], 0, 0, 0); \
      acc[1] = __builtin_amdgcn_mfma_f32_16x16x32_f16(s2[1].h, hf15, acc[1], 0, 0, 0); \
      acc[2] = __builtin_amdgcn_mfma_f32_16x16x32_f16(s3[0].h, hf15, acc[2], 0, 0, 0); \
      acc[3] = __builtin_amdgcn_mfma_f32_16x16x32_f16(s3[1].h, hf15, acc[3], 0, 0, 0); \
    }                                                                             \
    _Pragma("unroll")                                                             \
    for (int mt = 0; mt < 4; ++mt) {                                              \
      U4 o;                                                                       \
      _Pragma("unroll")                                                           \
      for (int r = 0; r < 4; ++r) {                                               \
        float z = acc[mt][r];                                                     \
        float e = __builtin_amdgcn_exp2f(z * 2.885390081777927f);                 \
        o.h[r] = (f16)(1.0f - 2.0f * __builtin_amdgcn_rcpf(e + 1.0f));            \
      }                                                                           \
      *(uint2*)((HW) + lr * 512 + ((w * 64 + mt * 16 + lg * 4) ^ asw)) = o.u;     \
    }                                                                             \
    __syncthreads();                                                              \
  } while (0)

__global__ __launch_bounds__(512, 2)
void phaseB_kernel(const u16* __restrict__ Whf, const u16* __restrict__ xpf,
                   float* __restrict__ out) {
  __shared__ f16 hb0[16 * 512];  // 16 KB (even steps read)
  __shared__ f16 hb1[16 * 512];  // 16 KB
  const int tid = threadIdx.x, w = tid >> 6, l = tid & 63;
  const int bb = blockIdx.x;
  const int lr = l & 15, lg = l >> 4;
  const int asw = (lr & 7) << 3;

  // W head resident (AGPR-class): wa[kt][mt], frag f = kt*32 + w*4 + mt
  f16x8 wa[12][4];
#pragma unroll
  for (int kt = 0; kt < 12; ++kt)
#pragma unroll
    for (int mt = 0; mt < 4; ++mt) {
      U8 u; u.u = *(const uint4*)(Whf + (size_t)(kt * 32 + w * 4 + mt) * 512 + l * 8);
      wa[kt][mt] = u.h;
    }
  { // h0 = 0 (hb1 fully written before first read)
    float* hz = (float*)hb0;
#pragma unroll
    for (int i = 0; i < 8; ++i) hz[i * 512 + tid] = 0.f;
  }
  __syncthreads();

  // invariants: W-tail L2 base (per-wave 16 KB chunk), xp base
  const u16* gt  = Whf + (size_t)(384 + w * 16) * 512 + l * 8;
  const u16* xpb = xpf + (size_t)(w * 16 + lg) * 1024 + (bb * 16 + lr) * 4;

  uint2 xpA[4], xpB[4];
#pragma unroll
  for (int mt = 0; mt < 4; ++mt) xpA[mt] = *(const uint2*)(xpb + mt * 4096);

#pragma unroll 1
  for (int t2 = 0; t2 < 256; ++t2) {
    const int t = t2 * 2;
    STEP(t,     hb0, hb1, xpA, xpB);   // even: read hb0, write hb1
    STEP(t + 1, hb1, hb0, xpB, xpA);   // odd : read hb1, write hb0
  }

  // final h in hb0 (step 511 wrote it; STEP ends with barrier)
#pragma unroll
  for (int i = 0; i < 16; ++i) {
    f16 v = hb0[i * 512 + (tid ^ ((i & 7) << 3))];
    out[(size_t)(bb * 16 + i) * 512 + tid] = (float)v;
  }
}

#undef STEP
#undef TL2
#undef MF_HEAD
#undef HFRAG

// ------------------------------------------------------------------ launch --
extern "C" void kernel_launch(void* const* d_in, const int* in_sizes, int n_in,
                              void* d_out, int out_size, void* d_ws, size_t ws_size,
                              hipStream_t stream) {
  const int*   X    = (const int*)d_in[0];
  const float* emb  = (const float*)d_in[1];
  const float* W_hh = (const float*)d_in[2];
  const float* b_hh = (const float*)d_in[3];
  const float* W_xh = (const float*)d_in[4];
  const float* b_xh = (const float*)d_in[5];
  float* out = (float*)d_out;

  char* ws = (char*)d_ws;
  u16* Whf = (u16*)ws;                    // 512 KB
  u16* Wxf = (u16*)(ws + 524288);         // 256 KB
  u16* xpf = (u16*)(ws + 786432);         // 128 MB

  preconv_kernel<<<128, 256, 0, stream>>>(W_hh, Whf, 512, 1);
  preconv_kernel<<< 64, 256, 0, stream>>>(W_xh, Wxf, 256, 0);
  phaseA_kernel<<<1024, 512, 0, stream>>>(X, emb, Wxf, b_hh, b_xh, xpf);
  phaseB_kernel<<<16, 512, 0, stream>>>(Whf, xpf, out);
}

// Round 15
// 1505.673 us; speedup vs baseline: 1.4845x; 1.4845x over previous
//
#include <hip/hip_runtime.h>

// SimpleRNN: VOCAB=32000, EMBED=256, HIDDEN=512, N=256, L=512
// out = h_512 (256x512 f32), h_{t+1} = tanh(h W_hh^T + b_hh + b_xh + emb[X] W_xh^T)
//
// Round-15 = round-14 resubmitted (round 14 was an infra failure, never ran).
// = round-6 (1045us, the only clean-codegen W-resident config) with ONE
// r6-proven-mechanism change: W residency 12 -> 13 kt (208+16acc = 224
// AGPR-class regs <= 256), LDS tail 4 -> 3 kt (96 KB). Removes 32 of 256
// LDS b128 reads/CU/step. r10-r13's L2-streaming abandoned: 4 different
// stagings -> identical counters (compiler normalizes + fixed 10MB spill).

typedef _Float16 f16;
typedef f16 f16x8 __attribute__((ext_vector_type(8)));
typedef float f32x4 __attribute__((ext_vector_type(4)));
typedef unsigned short u16;

union U8 { uint4 u; f16x8 h; };
union U4 { uint2 u; f16 h[4]; };

// ---------------------------------------------------------------- preconv ---
// One frag = 64 lanes x 8 f16 (1KB). lane l supplies W[col = c16*16 + (l&15)][k = kt*32 + (l>>4)*8 + j].
// mode 0 (W_xh, K=256): f = c16*8 + kt    [round-6 phaseA layout, known-good]
// mode 1 (W_hh, K=512): f = kt*32 + c16   [uniform; head+tail one formula]
__global__ void preconv_kernel(const float* __restrict__ W, u16* __restrict__ dst,
                               int kstride, int mode) {
  int t = blockIdx.x * blockDim.x + threadIdx.x;
  int f = t >> 6, l = t & 63;
  int kt, c16;
  if (mode == 0) { kt = f & 7;  c16 = f >> 3; }
  else           { kt = f >> 5; c16 = f & 31; }
  int col = c16 * 16 + (l & 15);
  int k   = kt * 32 + (l >> 4) * 8;
  const float* src = W + (size_t)col * kstride + k;
  float4 v0 = *(const float4*)src;
  float4 v1 = *(const float4*)(src + 4);
  U8 r;
  r.h = (f16x8){(f16)v0.x, (f16)v0.y, (f16)v0.z, (f16)v0.w,
                (f16)v1.x, (f16)v1.y, (f16)v1.z, (f16)v1.w};
  *(uint4*)(dst + (size_t)f * 512 + l * 8) = r.u;
}

// ----------------------------------------------------------------- phaseA ---
// Round-6 exact (known-good). Grid 1024 = 16 bn x 64 bl. 512 thr, 8 waves.
// Writes xpf[t][cq][n][4] f16, cq = out_col>>2 (0..127), n = batch row, biases folded.
__global__ __launch_bounds__(512, 2) void phaseA_kernel(
    const int* __restrict__ X, const float* __restrict__ emb,
    const u16* __restrict__ Wxf, const float* __restrict__ b_hh,
    const float* __restrict__ b_xh, u16* __restrict__ xpf) {
  __shared__ f16 A[128 * 256];  // 64 KB
  const int tid = threadIdx.x, w = tid >> 6, l = tid & 63;
  const int b = blockIdx.x, bn = b >> 6, bl = b & 63;
  const int lr = l & 15, lg = l >> 4;

  f16x8 wx[4][8];
#pragma unroll
  for (int mt = 0; mt < 4; ++mt)
#pragma unroll
    for (int kt = 0; kt < 8; ++kt) {
      U8 u; u.u = *(const uint4*)(Wxf + (size_t)((w * 4 + mt) * 8 + kt) * 512 + l * 8);
      wx[mt][kt] = u.h;
    }
  float bias[4][4];
#pragma unroll
  for (int mt = 0; mt < 4; ++mt)
#pragma unroll
    for (int r = 0; r < 4; ++r) {
      int c = w * 64 + mt * 16 + lg * 4 + r;
      bias[mt][r] = b_hh[c] + b_xh[c];
    }

  int xs[16];
  const int lseq = bl * 8 + w;
#pragma unroll
  for (int i = 0; i < 16; ++i) xs[i] = X[(bn * 16 + i) * 512 + lseq];
#pragma unroll
  for (int i = 0; i < 16; ++i) {
    float4 v = *(const float4*)(emb + (size_t)xs[i] * 256 + l * 4);
    U4 p; p.h[0] = (f16)v.x; p.h[1] = (f16)v.y; p.h[2] = (f16)v.z; p.h[3] = (f16)v.w;
    int row = w * 16 + i;
    *(uint2*)(&A[row * 256 + ((l * 4) ^ ((row & 7) << 3))]) = p.u;
  }
  __syncthreads();

#pragma unroll 1
  for (int nt = 0; nt < 8; ++nt) {
    f32x4 acc[4];
#pragma unroll
    for (int mt = 0; mt < 4; ++mt) acc[mt] = (f32x4){0.f, 0.f, 0.f, 0.f};
    const f16* Brow = &A[(nt * 16 + lr) * 256];
    const int sw = (lr & 7) << 3;
#pragma unroll
    for (int kt = 0; kt < 8; ++kt) {
      f16x8 bfr = *(const f16x8*)(Brow + ((kt * 32 + lg * 8) ^ sw));
#pragma unroll
      for (int mt = 0; mt < 4; ++mt)
        acc[mt] = __builtin_amdgcn_mfma_f32_16x16x32_f16(wx[mt][kt], bfr, acc[mt], 0, 0, 0);
    }
    const int t = bl * 8 + nt;
#pragma unroll
    for (int mt = 0; mt < 4; ++mt) {
      U4 p;
#pragma unroll
      for (int r = 0; r < 4; ++r) p.h[r] = (f16)(acc[mt][r] + bias[mt][r]);
      *(uint2*)(xpf + (size_t)t * 131072 + (w * 16 + mt * 4 + lg) * 1024
                    + (bn * 16 + lr) * 4) = p.u;
    }
  }
}

// ----------------------------------------------------------------- phaseB ---
// 16 blocks x 512 thr (8 waves, 2/SIMD). Block bb: batch rows [16bb,16bb+16).
// Wave w: out cols [64w,64w+64) (c16 = w*4+mt, mt=0..3). Transposed MFMA:
// acc[mt] = sum_kt mfma(Wfrag[kt][mt], hfrag[kt]); D row = out-col lg*4+r,
// D col = batch lr. h[16][512] f16 dbuf, storage row*512 + (col^((row&7)<<3)).
// W: kt0..12 resident (AGPR class, 208 regs); kt13..15 in LDS (96 KB).

#define HFRAG(HR, KT) (*(const f16x8*)((HR) + lr * 512 + (((KT) * 32 + lg * 8) ^ asw)))

#define STEP(T, HR, HW, XPc, XPn)                                                 \
  do {                                                                            \
    { /* prefetch xp for step T+1 (clamped, in-bounds) */                         \
      const int tn = ((T) + 1 < 512) ? ((T) + 1) : 511;                           \
      const u16* p = xpb + (size_t)tn * 131072;                                   \
      _Pragma("unroll")                                                           \
      for (int mt = 0; mt < 4; ++mt) XPn[mt] = *(const uint2*)(p + mt * 4096);    \
    }                                                                             \
    f32x4 acc[4];                                                                 \
    _Pragma("unroll")                                                             \
    for (int mt = 0; mt < 4; ++mt) acc[mt] = (f32x4){0.f, 0.f, 0.f, 0.f};         \
    _Pragma("unroll")                                                             \
    for (int kt = 0; kt < 13; ++kt) {   /* head: W resident */                    \
      f16x8 hf = HFRAG(HR, kt);                                                   \
      _Pragma("unroll")                                                           \
      for (int mt = 0; mt < 4; ++mt)                                              \
        acc[mt] = __builtin_amdgcn_mfma_f32_16x16x32_f16(wa[kt][mt], hf, acc[mt], 0, 0, 0); \
    }                                                                             \
    _Pragma("unroll")                                                             \
    for (int kt = 13; kt < 16; ++kt) {  /* tail: W from LDS, static offsets */    \
      f16x8 hf = HFRAG(HR, kt);                                                   \
      _Pragma("unroll")                                                           \
      for (int mt = 0; mt < 4; ++mt) {                                            \
        U8 u; u.u = *(const uint4*)(wt + (size_t)(((kt - 13) * 32 + mt)) * 512);  \
        acc[mt] = __builtin_amdgcn_mfma_f32_16x16x32_f16(u.h, hf, acc[mt], 0, 0, 0); \
      }                                                                           \
    }                                                                             \
    _Pragma("unroll")                                                             \
    for (int mt = 0; mt < 4; ++mt) {                                              \
      U4 px; px.u = XPc[mt];                                                      \
      U4 o;                                                                       \
      _Pragma("unroll")                                                           \
      for (int r = 0; r < 4; ++r) {                                               \
        float z = acc[mt][r] + (float)px.h[r];                                    \
        float e = __builtin_amdgcn_exp2f(z * 2.885390081777927f);                 \
        o.h[r] = (f16)(1.0f - 2.0f * __builtin_amdgcn_rcpf(e + 1.0f));            \
      }                                                                           \
      *(uint2*)((HW) + lr * 512 + ((w * 64 + mt * 16 + lg * 4) ^ asw)) = o.u;     \
    }                                                                             \
    __syncthreads();                                                              \
  } while (0)

__global__ __launch_bounds__(512)
__attribute__((amdgpu_waves_per_eu(2, 2)))
void phaseB_kernel(const u16* __restrict__ Whf, const u16* __restrict__ xpf,
                   float* __restrict__ out) {
  extern __shared__ char smem[];
  f16* hb0 = (f16*)smem;                   // 16 KB (even steps read)
  f16* hb1 = (f16*)(smem + 16 * 1024);     // 16 KB
  u16* wl  = (u16*)(smem + 32 * 1024);     // 96 KB: W tail frags 416..511 linear
  const int tid = threadIdx.x, w = tid >> 6, l = tid & 63;
  const int bb = blockIdx.x;
  const int lr = l & 15, lg = l >> 4;
  const int asw = (lr & 7) << 3;

  // W head resident: wa[kt][mt], frag f = kt*32 + w*4 + mt (208 regs, AGPR class)
  f16x8 wa[13][4];
#pragma unroll
  for (int kt = 0; kt < 13; ++kt)
#pragma unroll
    for (int mt = 0; mt < 4; ++mt) {
      U8 u; u.u = *(const uint4*)(Whf + (size_t)(kt * 32 + w * 4 + mt) * 512 + l * 8);
      wa[kt][mt] = u.h;
    }
  { // tail copy: frags 416..511 = 96 KB contiguous -> linear LDS
    const uint4* src = (const uint4*)(Whf + (size_t)416 * 512);
    uint4* dst = (uint4*)wl;
#pragma unroll
    for (int i = 0; i < 12; ++i) dst[i * 512 + tid] = src[i * 512 + tid];
  }
  { // h0 = 0 (hb1 fully written before first read)
    float* hz = (float*)hb0;
#pragma unroll
    for (int i = 0; i < 8; ++i) hz[i * 512 + tid] = 0.f;
  }
  __syncthreads();

  // invariants: tail LDS base (wave chunk = frags (kt-13)*32 + w*4 + mt), xp base
  const u16* wt  = wl + (size_t)(w * 4) * 512 + l * 8;
  const u16* xpb = xpf + (size_t)(w * 16 + lg) * 1024 + (bb * 16 + lr) * 4;

  uint2 xpA[4], xpB[4];
#pragma unroll
  for (int mt = 0; mt < 4; ++mt) xpA[mt] = *(const uint2*)(xpb + mt * 4096);

#pragma unroll 1
  for (int t2 = 0; t2 < 256; ++t2) {
    const int t = t2 * 2;
    STEP(t,     hb0, hb1, xpA, xpB);   // even: read hb0, write hb1
    STEP(t + 1, hb1, hb0, xpB, xpA);   // odd : read hb1, write hb0
  }

  // final h in hb0 (step 511 wrote it; STEP ends with barrier)
#pragma unroll
  for (int i = 0; i < 16; ++i) {
    f16 v = hb0[i * 512 + (tid ^ ((i & 7) << 3))];
    out[(size_t)(bb * 16 + i) * 512 + tid] = (float)v;
  }
}

#undef STEP
#undef HFRAG

// ------------------------------------------------------------------ launch --
extern "C" void kernel_launch(void* const* d_in, const int* in_sizes, int n_in,
                              void* d_out, int out_size, void* d_ws, size_t ws_size,
                              hipStream_t stream) {
  const int*   X    = (const int*)d_in[0];
  const float* emb  = (const float*)d_in[1];
  const float* W_hh = (const float*)d_in[2];
  const float* b_hh = (const float*)d_in[3];
  const float* W_xh = (const float*)d_in[4];
  const float* b_xh = (const float*)d_in[5];
  float* out = (float*)d_out;

  char* ws = (char*)d_ws;
  u16* Whf = (u16*)ws;                    // 512 KB
  u16* Wxf = (u16*)(ws + 524288);         // 256 KB
  u16* xpf = (u16*)(ws + 786432);         // 128 MB

  hipFuncSetAttribute((const void*)phaseB_kernel,
                      hipFuncAttributeMaxDynamicSharedMemorySize, 131072);

  preconv_kernel<<<128, 256, 0, stream>>>(W_hh, Whf, 512, 1);
  preconv_kernel<<< 64, 256, 0, stream>>>(W_xh, Wxf, 256, 0);
  phaseA_kernel<<<1024, 512, 0, stream>>>(X, emb, Wxf, b_hh, b_xh, xpf);
  phaseB_kernel<<<16, 512, 131072, stream>>>(Whf, xpf, out);
}